// Round 3
// 187.739 us; speedup vs baseline: 1.0708x; 1.0708x over previous
//
#include <hip/hip_runtime.h>
#include <hip/hip_bf16.h>

// GraphFourierLayer: B=32, N=4096, C_IN=128, C_OUT=128, M=256
#define BB 32
#define NN 4096
#define CI 128
#define CO 128
#define MM 256
#define KS 8           // K-split factor for stage 1 (N=4096 -> 8 chunks of 512)

typedef __hip_bfloat16 bf16;
typedef __attribute__((ext_vector_type(8))) short bf16x8;
typedef __attribute__((ext_vector_type(4))) float f32x4;

__device__ inline void gl_lds16(const void* g, void* l) {
    __builtin_amdgcn_global_load_lds(
        (const __attribute__((address_space(1))) void*)g,
        (__attribute__((address_space(3))) void*)l, 16, 0, 0);
}

// ---------------------------------------------------------------------------
// Prep 1: U fp32 [N][M] -> Un bf16 [N][M] (stage-3 A) and Ut bf16 [M][N]
// ---------------------------------------------------------------------------
__global__ __launch_bounds__(256) void k_cvtU(const float* __restrict__ U,
                                              bf16* __restrict__ Un,
                                              bf16* __restrict__ Ut) {
    const int n0 = blockIdx.x * 64;
    const int m0 = blockIdx.y * 64;
    __shared__ float tile[64][65];
    const int t = threadIdx.x;
    #pragma unroll
    for (int i = 0; i < 16; ++i) {
        int lin = t + i * 256;
        int r = lin >> 6, c = lin & 63;
        float v = U[(n0 + r) * MM + m0 + c];
        tile[r][c] = v;
        Un[(n0 + r) * MM + m0 + c] = __float2bfloat16(v);
    }
    __syncthreads();
    #pragma unroll
    for (int pass = 0; pass < 2; ++pass) {
        int no = t & 7;                    // n-octet
        int m  = (t >> 3) + pass * 32;     // m-local
        bf16 tmp[8];
        #pragma unroll
        for (int j = 0; j < 8; ++j) tmp[j] = __float2bfloat16(tile[no * 8 + j][m]);
        *(bf16x8*)&Ut[(long)(m0 + m) * NN + n0 + no * 8] = *(bf16x8*)tmp;
    }
}

// ---------------------------------------------------------------------------
// Prep 2: W fp32 [C][O][M] -> Wt bf16 [M][C][O]
// ---------------------------------------------------------------------------
__global__ __launch_bounds__(256) void k_wt(const float* __restrict__ W,
                                            bf16* __restrict__ Wt) {
    const int m0 = blockIdx.x * 64;
    const int o0 = blockIdx.y * 64;
    const int c  = blockIdx.z;
    __shared__ float tile[64][65];
    const int t = threadIdx.x;
    #pragma unroll
    for (int pass = 0; pass < 4; ++pass) {
        int r  = (t >> 4) + pass * 16;     // o-local
        int m4 = (t & 15) * 4;             // m-local
        float4 v = *(const float4*)&W[((long)c * CO + o0 + r) * MM + m0 + m4];
        tile[r][m4 + 0] = v.x; tile[r][m4 + 1] = v.y;
        tile[r][m4 + 2] = v.z; tile[r][m4 + 3] = v.w;
    }
    __syncthreads();
    #pragma unroll
    for (int pass = 0; pass < 2; ++pass) {
        int oo = t & 7;                    // o-octet
        int m  = (t >> 3) + pass * 32;     // m-local
        bf16 tmp[8];
        #pragma unroll
        for (int j = 0; j < 8; ++j) tmp[j] = __float2bfloat16(tile[oo * 8 + j][m]);
        *(bf16x8*)&Wt[((long)(m0 + m) * CI + c) * CO + o0 + oo * 8] = *(bf16x8*)tmp;
    }
}

// ---------------------------------------------------------------------------
// Stage 1 fused (MFMA, K-split, in-kernel x transpose+convert):
//   part[ks][b][m][c] = sum_n Ut[m][n] * x[b][n][c]
// BM=256 (full M): each x element read+converted exactly once -> k_trx dead
// (-96 MB HBM, -1 launch). 512 threads (8 waves, 4m x 2c).
// SYNC STRUCTURE: full __syncthreads() only (vmcnt0+lgkm0+fence+barrier) --
// the round-0 raw-barrier/counted-vmcnt pipeline raced (failed verify).
// Double-buffered: STAGE(next) issued before transpose(current) so HBM
// latency partially hides under the transpose; mid-sync drains everything.
// Hazards: (a) transpose reads Xf[cur] -- staged at kt-1, drained by kt-1's
// MID sync, plus one more sync since. (b) MFMA reads Bs[cur] (cross-wave
// transpose writes) -- separated by MID sync. (c) STAGE(cur^1,kt+1) over-
// writes tile kt-1's buffers -- reads done before kt-1's TAIL sync, STAGE
// issued after it. All closed by full-fence barriers.
// ---------------------------------------------------------------------------
__global__ __launch_bounds__(512) void k_gemm1f(const bf16* __restrict__ Ut,
                                                const float* __restrict__ x,
                                                bf16* __restrict__ part) {
    const int ks = blockIdx.x;
    const int b  = blockIdx.y;
    __shared__ __align__(16) bf16  As[2][MM * 32];   // 32 KB
    __shared__ __align__(16) bf16  Bs[2][CI * 32];   // 16 KB
    __shared__ __align__(16) float Xf[2][32 * CI];   // 32 KB
    const int t    = threadIdx.x;
    const int lane = t & 63;
    const int wave = t >> 6;
    const int wm   = wave >> 1, wn = wave & 1;       // 4 x 2 waves
    const int fr   = lane & 15;
    const int kg   = (lane >> 4) * 8;
    f32x4 acc[4][4] = {};
    const long xrow  = (long)b * NN;
    const int  kbase = ks * 512;

    auto STAGE = [&](int buf, int kt) {
        const int k0 = kbase + kt * 32;
        #pragma unroll
        for (int i = 0; i < 2; ++i) {
            int lin = t + i * 512;
            {   // A: Ut[m][n], rows r = 0..255, 32 k each
                int r = lin >> 2, kk = (lin & 3) * 8;
                gl_lds16(&Ut[(long)r * NN + k0 + kk], &As[buf][lin * 8]);
            }
            {   // X: x[b][k0+r][c], fp32, linear [32][128]
                int r = lin >> 5, c4 = (lin & 31) * 4;
                gl_lds16(&x[(xrow + k0 + r) * CI + c4], &Xf[buf][lin * 4]);
            }
        }
    };

    const int NT = 512 / 32;   // 16
    STAGE(0, 0);
    __syncthreads();           // tile 0 fully in LDS
    #pragma unroll
    for (int kt = 0; kt < NT; ++kt) {
        const int cur = kt & 1;
        if (kt + 1 < NT) STAGE(cur ^ 1, kt + 1);   // async next-tile loads
        // transpose+convert Xf[cur] (fp32 [32 n][128 c]) -> Bs[cur] (bf16 [128 c][32 n])
        {
            const int c  = t & 127;
            const int nh = t >> 7;         // 0..3 -> n octet
            bf16 tmp[8];
            #pragma unroll
            for (int j = 0; j < 8; ++j)
                tmp[j] = __float2bfloat16(Xf[cur][(nh * 8 + j) * CI + c]);
            *(bf16x8*)&Bs[cur][c * 32 + nh * 8] = *(bf16x8*)tmp;
        }
        __syncthreads();        // drains transpose writes + next-tile loads
        bf16x8 a[4], bfr[4];
        #pragma unroll
        for (int i = 0; i < 4; ++i)
            a[i] = *(const bf16x8*)&As[cur][(wm * 64 + i * 16 + fr) * 32 + kg];
        #pragma unroll
        for (int j = 0; j < 4; ++j)
            bfr[j] = *(const bf16x8*)&Bs[cur][(wn * 64 + j * 16 + fr) * 32 + kg];
        #pragma unroll
        for (int i = 0; i < 4; ++i)
            #pragma unroll
            for (int j = 0; j < 4; ++j)
                acc[i][j] = __builtin_amdgcn_mfma_f32_16x16x32_bf16(a[i], bfr[j], acc[i][j], 0, 0, 0);
        __syncthreads();        // protect tile-kt buffers before restage at kt+1
    }
    const int quad = (lane >> 4) * 4;
    const long pbase = ((long)ks * BB + b) * MM * CI;
    #pragma unroll
    for (int i = 0; i < 4; ++i) {
        #pragma unroll
        for (int j = 0; j < 4; ++j) {
            int mg = wm * 64 + i * 16 + quad;
            int cg = wn * 64 + j * 16 + fr;
            #pragma unroll
            for (int r = 0; r < 4; ++r)
                part[pbase + (long)(mg + r) * CI + cg] = __float2bfloat16(acc[i][j][r]);
        }
    }
}

// ---------------------------------------------------------------------------
// Stage 2: reduce K-split partials + per-mode channel mix -> osT[b][o][m] bf16
// One block per mode (full 128-o): part slice read ONCE (16 MB vs 32 MB).
// ---------------------------------------------------------------------------
__global__ __launch_bounds__(256) void k_mix(const bf16* __restrict__ part,
                                             const bf16* __restrict__ Wt,
                                             bf16* __restrict__ osT) {
    const int blk = blockIdx.x;                 // 0..255
    const int m   = (blk & 7) * 32 + (blk >> 3); // XCD swizzle on mode
    __shared__ bf16  Wl[CI][CO];                // 32 KB, kept bf16
    __shared__ float xl[CI][36];                // 18 KB (+pad)
    const int t = threadIdx.x;
    const long wb = (long)m * CI * CO;
    #pragma unroll
    for (int i = 0; i < 8; ++i) {
        int ch = t + i * 256;
        int c = ch >> 4, og = (ch & 15) * 8;
        *(bf16x8*)&Wl[c][og] = *(const bf16x8*)&Wt[wb + (long)c * CO + og];
    }
    #pragma unroll
    for (int i = 0; i < 2; ++i) {
        int ch = t + i * 256;
        int b = ch >> 4, c8 = (ch & 15) * 8;
        float s[8] = {};
        #pragma unroll
        for (int ks = 0; ks < KS; ++ks) {
            bf16x8 v = *(const bf16x8*)&part[(((long)ks * BB + b) * MM + m) * CI + c8];
            #pragma unroll
            for (int j = 0; j < 8; ++j) s[j] += __bfloat162float(((const bf16*)&v)[j]);
        }
        #pragma unroll
        for (int j = 0; j < 8; ++j) xl[c8 + j][b] = s[j];
    }
    __syncthreads();
    const int o  = t & 127;
    const int bh = t >> 7;                      // 0..1 -> 16 b each
    float acc[16] = {};
    for (int c = 0; c < CI; ++c) {
        float w = __bfloat162float(Wl[c][o]);
        #pragma unroll
        for (int j = 0; j < 16; ++j)
            acc[j] += xl[c][bh * 16 + j] * w;
    }
    #pragma unroll
    for (int j = 0; j < 16; ++j)
        osT[((long)(bh * 16 + j) * CO + o) * MM + m] = __float2bfloat16(acc[j]);
}

// ---------------------------------------------------------------------------
// Stage 3 (MFMA): out[b][n][o] = sum_m Un[n][m] * osT[b][o][m]. K=256.
// BASELINE-VERBATIM (passing 201us version): single buffer, __syncthreads.
// The counted-vmcnt variant is deferred until it can be race-screened alone.
// ---------------------------------------------------------------------------
__global__ __launch_bounds__(256) void k_gemm3(const bf16* __restrict__ Un,
                                               const bf16* __restrict__ osT,
                                               float* __restrict__ out) {
    const int n0 = blockIdx.x * 128;
    const int b  = blockIdx.y;
    __shared__ __align__(16) bf16 As[128 * 32];
    __shared__ __align__(16) bf16 Bs[128 * 32];
    const int t    = threadIdx.x;
    const int lane = t & 63;
    const int wave = t >> 6;
    const int wm   = wave >> 1, wn = wave & 1;
    const int fr   = lane & 15;
    const int kg   = (lane >> 4) * 8;
    f32x4 acc[4][4] = {};
    const long bbase = (long)b * CO * MM;
    for (int kt = 0; kt < MM / 32; ++kt) {
        const int k0 = kt * 32;
        #pragma unroll
        for (int i = 0; i < 2; ++i) {
            int lin = t + i * 256;
            int r = lin >> 2, kk = (lin & 3) * 8;
            gl_lds16(&Un[(long)(n0 + r) * MM + k0 + kk], &As[lin * 8]);
            gl_lds16(&osT[bbase + (long)r * MM + k0 + kk], &Bs[lin * 8]);
        }
        __syncthreads();
        bf16x8 a[4], bfr[4];
        #pragma unroll
        for (int i = 0; i < 4; ++i)
            a[i] = *(const bf16x8*)&As[(wm * 64 + i * 16 + fr) * 32 + kg];
        #pragma unroll
        for (int j = 0; j < 4; ++j)
            bfr[j] = *(const bf16x8*)&Bs[(wn * 64 + j * 16 + fr) * 32 + kg];
        #pragma unroll
        for (int i = 0; i < 4; ++i)
            #pragma unroll
            for (int j = 0; j < 4; ++j)
                acc[i][j] = __builtin_amdgcn_mfma_f32_16x16x32_bf16(a[i], bfr[j], acc[i][j], 0, 0, 0);
        __syncthreads();
    }
    const int quad = (lane >> 4) * 4;
    #pragma unroll
    for (int i = 0; i < 4; ++i) {
        #pragma unroll
        for (int j = 0; j < 4; ++j) {
            int ng = n0 + wm * 64 + i * 16 + quad;
            int og = wn * 64 + j * 16 + fr;
            #pragma unroll
            for (int r = 0; r < 4; ++r)
                out[((long)b * NN + ng + r) * CO + og] = acc[i][j][r];
        }
    }
}

extern "C" void kernel_launch(void* const* d_in, const int* in_sizes, int n_in,
                              void* d_out, int out_size, void* d_ws, size_t ws_size,
                              hipStream_t stream) {
    const float* x  = (const float*)d_in[0];   // [32][4096][128]
    const float* U  = (const float*)d_in[1];   // [4096][256]
    const float* Wr = (const float*)d_in[2];   // [128][128][256]
    float* out = (float*)d_out;                // [32][4096][128]

    char* p = (char*)d_ws;
    bf16* part = (bf16*)p;  p += (size_t)KS * BB * MM * CI * 2;   // 16 MB
    bf16* Ut   = (bf16*)p;  p += (size_t)MM * NN * 2;             // 2 MB
    bf16* Un   = (bf16*)p;  p += (size_t)NN * MM * 2;             // 2 MB
    bf16* osT  = (bf16*)p;  p += (size_t)BB * CO * MM * 2;        // 2 MB
    bf16* Wt   = (bf16*)p;  p += (size_t)MM * CI * CO * 2;        // 8 MB

    k_cvtU  <<<dim3(NN / 64, MM / 64), 256, 0, stream>>>(U, Un, Ut);
    k_wt    <<<dim3(MM / 64, CO / 64, CI), 256, 0, stream>>>(Wr, Wt);
    k_gemm1f<<<dim3(KS, BB), 512, 0, stream>>>(Ut, x, part);
    k_mix   <<<dim3(256), 256, 0, stream>>>(part, Wt, osT);
    k_gemm3 <<<dim3(NN / 128, BB), 256, 0, stream>>>(Un, osT, out);
}

// Round 4
// 187.529 us; speedup vs baseline: 1.0720x; 1.0011x over previous
//
#include <hip/hip_runtime.h>
#include <hip/hip_bf16.h>

// GraphFourierLayer: B=32, N=4096, C_IN=128, C_OUT=128, M=256
#define BB 32
#define NN 4096
#define CI 128
#define CO 128
#define MM 256
#define KS 8           // K-split factor for stage 1 (N=4096 -> 8 chunks of 512)

typedef __hip_bfloat16 bf16;
typedef __attribute__((ext_vector_type(8))) short bf16x8;
typedef __attribute__((ext_vector_type(4))) float f32x4;

__device__ inline void gl_lds16(const void* g, void* l) {
    __builtin_amdgcn_global_load_lds(
        (const __attribute__((address_space(1))) void*)g,
        (__attribute__((address_space(3))) void*)l, 16, 0, 0);
}

// Compiler-only memory fence (no instructions). Raw s_barrier is NOT a
// compiler fence: without this, LDS reads hoist above / sink below it at the
// IR level (the round-0 race). Wrap every raw barrier: FENCE; BAR; FENCE.
#define CFENCE() asm volatile("" ::: "memory")
#define BAR()    __builtin_amdgcn_s_barrier()

// ---------------------------------------------------------------------------
// Prep 1: U fp32 [N][M] -> Un bf16 [N][M] (stage-3 A) and Ut bf16 [M][N]
// ---------------------------------------------------------------------------
__global__ __launch_bounds__(256) void k_cvtU(const float* __restrict__ U,
                                              bf16* __restrict__ Un,
                                              bf16* __restrict__ Ut) {
    const int n0 = blockIdx.x * 64;
    const int m0 = blockIdx.y * 64;
    __shared__ float tile[64][65];
    const int t = threadIdx.x;
    #pragma unroll
    for (int i = 0; i < 16; ++i) {
        int lin = t + i * 256;
        int r = lin >> 6, c = lin & 63;
        float v = U[(n0 + r) * MM + m0 + c];
        tile[r][c] = v;
        Un[(n0 + r) * MM + m0 + c] = __float2bfloat16(v);
    }
    __syncthreads();
    #pragma unroll
    for (int pass = 0; pass < 2; ++pass) {
        int no = t & 7;                    // n-octet
        int m  = (t >> 3) + pass * 32;     // m-local
        bf16 tmp[8];
        #pragma unroll
        for (int j = 0; j < 8; ++j) tmp[j] = __float2bfloat16(tile[no * 8 + j][m]);
        *(bf16x8*)&Ut[(long)(m0 + m) * NN + n0 + no * 8] = *(bf16x8*)tmp;
    }
}

// ---------------------------------------------------------------------------
// Prep 2: W fp32 [C][O][M] -> Wt bf16 [M][C][O]
// ---------------------------------------------------------------------------
__global__ __launch_bounds__(256) void k_wt(const float* __restrict__ W,
                                            bf16* __restrict__ Wt) {
    const int m0 = blockIdx.x * 64;
    const int o0 = blockIdx.y * 64;
    const int c  = blockIdx.z;
    __shared__ float tile[64][65];
    const int t = threadIdx.x;
    #pragma unroll
    for (int pass = 0; pass < 4; ++pass) {
        int r  = (t >> 4) + pass * 16;     // o-local
        int m4 = (t & 15) * 4;             // m-local
        float4 v = *(const float4*)&W[((long)c * CO + o0 + r) * MM + m0 + m4];
        tile[r][m4 + 0] = v.x; tile[r][m4 + 1] = v.y;
        tile[r][m4 + 2] = v.z; tile[r][m4 + 3] = v.w;
    }
    __syncthreads();
    #pragma unroll
    for (int pass = 0; pass < 2; ++pass) {
        int oo = t & 7;                    // o-octet
        int m  = (t >> 3) + pass * 32;     // m-local
        bf16 tmp[8];
        #pragma unroll
        for (int j = 0; j < 8; ++j) tmp[j] = __float2bfloat16(tile[oo * 8 + j][m]);
        *(bf16x8*)&Wt[((long)(m0 + m) * CI + c) * CO + o0 + oo * 8] = *(bf16x8*)tmp;
    }
}

// ---------------------------------------------------------------------------
// Stage 1 fused (MFMA, K-split, in-kernel x transpose+convert):
//   part[ks][b][m][c] = sum_n Ut[m][n] * x[b][n][c]
// BM=256 (full M): x read once. 512 threads (8 waves, 4m x 2c).
// SAFE all-__syncthreads structure, REORDERED vs round 3: the next-tile
// STAGE is issued at the top of the MFMA phase, so the tail sync's vmcnt
// drain is covered by ds_read+MFMA (~300cy) instead of the transpose
// (~150cy). Mid sync drains nothing (no loads outstanding there).
// Hazards (all closed by full-fence __syncthreads):
//  - transpose reads Xf[cur]: staged in kt-1's MFMA phase, drained at kt-1
//    tail sync.
//  - MFMA reads Bs[cur] (cross-wave transpose writes): mid sync.
//  - STAGE(cur^1) overwrites As/Xf[cur^1], last read in kt-1's MFMA phase
//    (As) / kt-1's transpose (Xf), both before kt-1 tail sync; STAGE is
//    issued two syncs later.
// ---------------------------------------------------------------------------
__global__ __launch_bounds__(512) void k_gemm1f(const bf16* __restrict__ Ut,
                                                const float* __restrict__ x,
                                                bf16* __restrict__ part) {
    const int ks = blockIdx.x;
    const int b  = blockIdx.y;
    __shared__ __align__(16) bf16  As[2][MM * 32];   // 32 KB
    __shared__ __align__(16) bf16  Bs[2][CI * 32];   // 16 KB
    __shared__ __align__(16) float Xf[2][32 * CI];   // 32 KB
    const int t    = threadIdx.x;
    const int lane = t & 63;
    const int wave = t >> 6;
    const int wm   = wave >> 1, wn = wave & 1;       // 4 x 2 waves
    const int fr   = lane & 15;
    const int kg   = (lane >> 4) * 8;
    f32x4 acc[4][4] = {};
    const long xrow  = (long)b * NN;
    const int  kbase = ks * 512;

    auto STAGE = [&](int buf, int kt) {
        const int k0 = kbase + kt * 32;
        #pragma unroll
        for (int i = 0; i < 2; ++i) {
            int lin = t + i * 512;
            {   // A: Ut[m][n], rows r = 0..255, 32 k each
                int r = lin >> 2, kk = (lin & 3) * 8;
                gl_lds16(&Ut[(long)r * NN + k0 + kk], &As[buf][lin * 8]);
            }
            {   // X: x[b][k0+r][c], fp32, linear [32][128]
                int r = lin >> 5, c4 = (lin & 31) * 4;
                gl_lds16(&x[(xrow + k0 + r) * CI + c4], &Xf[buf][lin * 4]);
            }
        }
    };

    const int NT = 512 / 32;   // 16
    STAGE(0, 0);
    __syncthreads();           // tile 0 fully in LDS
    #pragma unroll
    for (int kt = 0; kt < NT; ++kt) {
        const int cur = kt & 1;
        // transpose+convert Xf[cur] (fp32 [32 n][128 c]) -> Bs[cur] (bf16 [128 c][32 n])
        {
            const int c  = t & 127;
            const int nh = t >> 7;         // 0..3 -> n octet
            bf16 tmp[8];
            #pragma unroll
            for (int j = 0; j < 8; ++j)
                tmp[j] = __float2bfloat16(Xf[cur][(nh * 8 + j) * CI + c]);
            *(bf16x8*)&Bs[cur][c * 32 + nh * 8] = *(bf16x8*)tmp;
        }
        __syncthreads();        // Bs[cur] visible; nothing outstanding -> cheap
        if (kt + 1 < NT) STAGE(cur ^ 1, kt + 1);   // loads fly under MFMA phase
        bf16x8 a[4], bfr[4];
        #pragma unroll
        for (int i = 0; i < 4; ++i)
            a[i] = *(const bf16x8*)&As[cur][(wm * 64 + i * 16 + fr) * 32 + kg];
        #pragma unroll
        for (int j = 0; j < 4; ++j)
            bfr[j] = *(const bf16x8*)&Bs[cur][(wn * 64 + j * 16 + fr) * 32 + kg];
        #pragma unroll
        for (int i = 0; i < 4; ++i)
            #pragma unroll
            for (int j = 0; j < 4; ++j)
                acc[i][j] = __builtin_amdgcn_mfma_f32_16x16x32_bf16(a[i], bfr[j], acc[i][j], 0, 0, 0);
        __syncthreads();        // drains next-tile loads (MFMA-covered) + protects bufs
    }
    const int quad = (lane >> 4) * 4;
    const long pbase = ((long)ks * BB + b) * MM * CI;
    #pragma unroll
    for (int i = 0; i < 4; ++i) {
        #pragma unroll
        for (int j = 0; j < 4; ++j) {
            int mg = wm * 64 + i * 16 + quad;
            int cg = wn * 64 + j * 16 + fr;
            #pragma unroll
            for (int r = 0; r < 4; ++r)
                part[pbase + (long)(mg + r) * CI + cg] = __float2bfloat16(acc[i][j][r]);
        }
    }
}

// ---------------------------------------------------------------------------
// Stage 2: reduce K-split partials + per-mode channel mix -> osT[b][o][m] bf16
// One block per mode (full 128-o): part slice read ONCE (16 MB vs 32 MB).
// ---------------------------------------------------------------------------
__global__ __launch_bounds__(256) void k_mix(const bf16* __restrict__ part,
                                             const bf16* __restrict__ Wt,
                                             bf16* __restrict__ osT) {
    const int blk = blockIdx.x;                 // 0..255
    const int m   = (blk & 7) * 32 + (blk >> 3); // XCD swizzle on mode
    __shared__ bf16  Wl[CI][CO];                // 32 KB, kept bf16
    __shared__ float xl[CI][36];                // 18 KB (+pad)
    const int t = threadIdx.x;
    const long wb = (long)m * CI * CO;
    #pragma unroll
    for (int i = 0; i < 8; ++i) {
        int ch = t + i * 256;
        int c = ch >> 4, og = (ch & 15) * 8;
        *(bf16x8*)&Wl[c][og] = *(const bf16x8*)&Wt[wb + (long)c * CO + og];
    }
    #pragma unroll
    for (int i = 0; i < 2; ++i) {
        int ch = t + i * 256;
        int b = ch >> 4, c8 = (ch & 15) * 8;
        float s[8] = {};
        #pragma unroll
        for (int ks = 0; ks < KS; ++ks) {
            bf16x8 v = *(const bf16x8*)&part[(((long)ks * BB + b) * MM + m) * CI + c8];
            #pragma unroll
            for (int j = 0; j < 8; ++j) s[j] += __bfloat162float(((const bf16*)&v)[j]);
        }
        #pragma unroll
        for (int j = 0; j < 8; ++j) xl[c8 + j][b] = s[j];
    }
    __syncthreads();
    const int o  = t & 127;
    const int bh = t >> 7;                      // 0..1 -> 16 b each
    float acc[16] = {};
    for (int c = 0; c < CI; ++c) {
        float w = __bfloat162float(Wl[c][o]);
        #pragma unroll
        for (int j = 0; j < 16; ++j)
            acc[j] += xl[c][bh * 16 + j] * w;
    }
    #pragma unroll
    for (int j = 0; j < 16; ++j)
        osT[((long)(bh * 16 + j) * CO + o) * MM + m] = __float2bfloat16(acc[j]);
}

// ---------------------------------------------------------------------------
// Stage 3 (MFMA): out[b][n][o] = sum_m Un[n][m] * osT[b][o][m]. K=256.
// FENCED counted-vmcnt 2-phase (the isolated risky change this round):
//  - per-wave vmcnt(4): current tile's 4 gl_lds retired, next tile's 4 stay
//    in flight across the MFMA phase (never drains to 0 in main loop)
//  - every raw barrier wrapped in CFENCE (compiler ordering; round-0's race
//    was LDS reads hoisting above an unfenced s_barrier)
// ---------------------------------------------------------------------------
__global__ __launch_bounds__(256) void k_gemm3(const bf16* __restrict__ Un,
                                               const bf16* __restrict__ osT,
                                               float* __restrict__ out) {
    const int n0 = blockIdx.x * 128;
    const int b  = blockIdx.y;
    __shared__ __align__(16) bf16 As[2][128 * 32];
    __shared__ __align__(16) bf16 Bs[2][128 * 32];
    const int t    = threadIdx.x;
    const int lane = t & 63;
    const int wave = t >> 6;
    const int wm   = wave >> 1, wn = wave & 1;
    const int fr   = lane & 15;
    const int kg   = (lane >> 4) * 8;
    f32x4 acc[4][4] = {};
    const long bbase = (long)b * CO * MM;

    auto STAGE = [&](int buf, int kt) {
        const int k0 = kt * 32;
        #pragma unroll
        for (int i = 0; i < 2; ++i) {
            int lin = t + i * 256;
            int r = lin >> 2, kk = (lin & 3) * 8;
            gl_lds16(&Un[(long)(n0 + r) * MM + k0 + kk], &As[buf][lin * 8]);
            gl_lds16(&osT[bbase + (long)r * MM + k0 + kk], &Bs[buf][lin * 8]);
        }
    };

    const int NT = MM / 32;   // 8
    STAGE(0, 0);
    #pragma unroll
    for (int kt = 0; kt < NT; ++kt) {
        const int cur = kt & 1;
        if (kt + 1 < NT) {
            STAGE(cur ^ 1, kt + 1);
            // own tile-kt loads retired (4 newer stay in flight)
            asm volatile("s_waitcnt vmcnt(4)" ::: "memory");
        } else {
            asm volatile("s_waitcnt vmcnt(0)" ::: "memory");
        }
        BAR(); CFENCE();          // join: all waves' tile-kt loads retired
        bf16x8 a[4], bfr[4];
        #pragma unroll
        for (int i = 0; i < 4; ++i)
            a[i] = *(const bf16x8*)&As[cur][(wm * 64 + i * 16 + fr) * 32 + kg];
        #pragma unroll
        for (int j = 0; j < 4; ++j)
            bfr[j] = *(const bf16x8*)&Bs[cur][(wn * 64 + j * 16 + fr) * 32 + kg];
        #pragma unroll
        for (int i = 0; i < 4; ++i)
            #pragma unroll
            for (int j = 0; j < 4; ++j)
                acc[i][j] = __builtin_amdgcn_mfma_f32_16x16x32_bf16(a[i], bfr[j], acc[i][j], 0, 0, 0);
        CFENCE(); BAR(); CFENCE();   // reads of buf[cur] done before restage at kt+1
    }
    const int quad = (lane >> 4) * 4;
    #pragma unroll
    for (int i = 0; i < 4; ++i) {
        #pragma unroll
        for (int j = 0; j < 4; ++j) {
            int ng = n0 + wm * 64 + i * 16 + quad;
            int og = wn * 64 + j * 16 + fr;
            #pragma unroll
            for (int r = 0; r < 4; ++r)
                out[((long)b * NN + ng + r) * CO + og] = acc[i][j][r];
        }
    }
}

extern "C" void kernel_launch(void* const* d_in, const int* in_sizes, int n_in,
                              void* d_out, int out_size, void* d_ws, size_t ws_size,
                              hipStream_t stream) {
    const float* x  = (const float*)d_in[0];   // [32][4096][128]
    const float* U  = (const float*)d_in[1];   // [4096][256]
    const float* Wr = (const float*)d_in[2];   // [128][128][256]
    float* out = (float*)d_out;                // [32][4096][128]

    char* p = (char*)d_ws;
    bf16* part = (bf16*)p;  p += (size_t)KS * BB * MM * CI * 2;   // 16 MB
    bf16* Ut   = (bf16*)p;  p += (size_t)MM * NN * 2;             // 2 MB
    bf16* Un   = (bf16*)p;  p += (size_t)NN * MM * 2;             // 2 MB
    bf16* osT  = (bf16*)p;  p += (size_t)BB * CO * MM * 2;        // 2 MB
    bf16* Wt   = (bf16*)p;  p += (size_t)MM * CI * CO * 2;        // 8 MB

    k_cvtU  <<<dim3(NN / 64, MM / 64), 256, 0, stream>>>(U, Un, Ut);
    k_wt    <<<dim3(MM / 64, CO / 64, CI), 256, 0, stream>>>(Wr, Wt);
    k_gemm1f<<<dim3(KS, BB), 512, 0, stream>>>(Ut, x, part);
    k_mix   <<<dim3(256), 256, 0, stream>>>(part, Wt, osT);
    k_gemm3 <<<dim3(NN / 128, BB), 256, 0, stream>>>(Un, osT, out);
}